// Round 21
// baseline (165.608 us; speedup 1.0000x reference)
//
#include <hip/hip_runtime.h>
#include <hip/hip_fp16.h>

#define B 8
#define C 64
#define H 128
#define W 128
#define HW (H * W)
#define OC 27
#define KK 9
#define COUT 64
#define KDIM 576           // 9*64
#define LDSROW 1152        // bytes per pixel row (576 * 2B)
#define NPIX 16            // pixels per k_main workgroup
#define NPAIR (NPIX * KK)  // 144

typedef __attribute__((ext_vector_type(8))) short s16x8;
typedef __attribute__((ext_vector_type(4))) float f32x4;

__device__ inline ushort f2bf(float f) {
    union { float f; unsigned u; } uv;
    uv.f = f;
    unsigned r = uv.u + 0x7FFF + ((uv.u >> 16) & 1);
    return (ushort)(r >> 16);
}
__device__ inline float bf2f(ushort u) {
    return __uint_as_float((unsigned)u << 16);
}
__device__ inline unsigned pkhalf2(float a, float b) {
    __half2 h = __floats2half2_rn(a, b);
    return *(unsigned*)&h;
}

// ---------------------------------------------------------------------------
// Kernel 1: transpose x (NCHW fp32) -> xTb (NHWC bf16). XCD-chunked swizzle.
// ---------------------------------------------------------------------------
__global__ __launch_bounds__(256) void k_transpose_x(const float* __restrict__ x,
                                                     ushort* __restrict__ xTb) {
    __shared__ float lds[64][65];
    int j = blockIdx.x;
    int vb = (j & 7) * 256 + (j >> 3);
    int b = vb >> 8;
    int tile = vb & 255;
    int hw0 = tile * 64;
    int lane = threadIdx.x & 63;
    int cg = threadIdx.x >> 6;
#pragma unroll
    for (int r = 0; r < 16; ++r) {
        int c = cg * 16 + r;
        lds[c][lane] = x[(size_t)(b * C + c) * HW + hw0 + lane];
    }
    __syncthreads();
    int c2 = (lane & 31) * 2;
#pragma unroll
    for (int r = 0; r < 8; ++r) {
        int hwl = cg * 16 + r * 2 + (lane >> 5);
        ushort2 v;
        v.x = f2bf(lds[c2][hwl]);
        v.y = f2bf(lds[c2 + 1][hwl]);
        *(ushort2*)&xTb[(size_t)(b * HW + hw0 + hwl) * C + c2] = v;
    }
}

// ---------------------------------------------------------------------------
// Kernel 2: repack w -> wB[o][K] bf16, K = tap*64 + c.
// ---------------------------------------------------------------------------
__global__ __launch_bounds__(256) void k_prep_w(const float* __restrict__ w,
                                                ushort* __restrict__ wB) {
    int idx = blockIdx.x * 256 + threadIdx.x;
    if (idx >= COUT * KDIM) return;
    int o = idx / KDIM;
    int Kx = idx % KDIM;
    int k = Kx >> 6;
    int c = Kx & 63;
    wB[idx] = f2bf(w[(size_t)(o * C + c) * KK + k]);
}

// ---------------------------------------------------------------------------
// Kernel 2b: repack ow -> awB[32][576] bf16 (rows 27..31 = 0).
// ---------------------------------------------------------------------------
__global__ __launch_bounds__(256) void k_prep_aw(const float* __restrict__ ow,
                                                 ushort* __restrict__ awB) {
    int idx = blockIdx.x * 256 + threadIdx.x;
    if (idx >= 32 * KDIM) return;
    int o = idx / KDIM;
    int Kx = idx % KDIM;
    int tap = Kx >> 6;
    int c = Kx & 63;
    float v = (o < OC) ? ow[((size_t)o * C + c) * KK + tap] : 0.0f;
    awB[idx] = f2bf(v);
}

// ---------------------------------------------------------------------------
// Kernel 3: offset/mask conv (im2col MFMA GEMM); uint4 staging; om written
// pixel-major [b][hw][32].
// ---------------------------------------------------------------------------
__global__ __launch_bounds__(256) void k_om(const ushort* __restrict__ xTb,
                                            const ushort* __restrict__ awB,
                                            const float* __restrict__ ob,
                                            float* __restrict__ om_pm) {
    __shared__ __align__(16) char xwin[3 * 66 * 128];  // 25344 B
    int tid = threadIdx.x;
    int lane = tid & 63;
    int wv = tid >> 6;
    int j = blockIdx.x;
    int vb = (j & 7) * 256 + (j >> 3);
    int b = vb >> 8;
    int h = (vb >> 1) & 127;
    int w0 = (vb & 1) * 64;

    const char* xb = (const char*)(xTb + (size_t)b * (HW * C));
#pragma unroll
    for (int i = 0; i < 7; ++i) {
        int idx = i * 256 + tid;
        if (idx < 198 * 8) {
            int pi = idx >> 3;
            int ch16 = idx & 7;
            int row = pi / 66;
            int col = pi - row * 66;
            int y = h - 1 + row;
            int xc = w0 - 1 + col;
            uint4 v = make_uint4(0, 0, 0, 0);
            if ((unsigned)y < H && (unsigned)xc < W)
                v = *(const uint4*)(xb + ((size_t)((y << 7) + xc) << 7) + ch16 * 16);
            int byte = (pi * 128 + ch16 * 16) ^ ((col & 7) << 4);
            *(uint4*)(xwin + byte) = v;
        }
    }
    __syncthreads();

    f32x4 acc0 = {0.f, 0.f, 0.f, 0.f};
    f32x4 acc1 = {0.f, 0.f, 0.f, 0.f};
    int pixl = lane & 15;
    int q = lane >> 4;
    int base_col = wv * 16 + pixl;
    const ushort* a0 = awB + (size_t)pixl * KDIM + q * 8;
    const ushort* a1 = awB + (size_t)(16 + pixl) * KDIM + q * 8;
#pragma unroll
    for (int s = 0; s < 18; ++s) {
        int tap = s >> 1;
        int row = tap / 3;
        int cs = tap - row * 3;
        int col = base_col + cs;
        int c0b = ((s & 1) * 32 + q * 8) * 2;
        int byte = (((row * 66 + col) << 7) + c0b) ^ ((col & 7) << 4);
        s16x8 bfrag = *(const s16x8*)(xwin + byte);
        s16x8 af0 = *(const s16x8*)(a0 + s * 32);
        s16x8 af1 = *(const s16x8*)(a1 + s * 32);
        acc0 = __builtin_amdgcn_mfma_f32_16x16x32_bf16(af0, bfrag, acc0, 0, 0, 0);
        acc1 = __builtin_amdgcn_mfma_f32_16x16x32_bf16(af1, bfrag, acc1, 0, 0, 0);
    }

    __syncthreads();
    float* omt = (float*)xwin;  // [64 pix][29]
    {
        int pix = wv * 16 + pixl;
#pragma unroll
        for (int jj = 0; jj < 4; ++jj) {
            int oc = q * 4 + jj;
            omt[pix * 29 + oc] = acc0[jj] + ob[oc];
        }
#pragma unroll
        for (int jj = 0; jj < 4; ++jj) {
            int oc1 = 16 + q * 4 + jj;
            if (oc1 < OC) omt[pix * 29 + oc1] = acc1[jj] + ob[oc1];
        }
    }
    __syncthreads();

    float* dst = om_pm + ((size_t)b * HW + h * W + w0) * 32;
#pragma unroll
    for (int t = tid; t < 64 * 32; t += 256) {
        int pix = t >> 5;
        int oc = t & 31;
        float v = (oc < OC) ? omt[pix * 29 + oc] : 0.0f;
        dst[(size_t)pix * 32 + oc] = v;
    }
}

// ---------------------------------------------------------------------------
// Kernel 4: fused deformable sampling + MFMA einsum. R14 structure; A1's 18
// gathers per pixel issued in ONE asm block (18 "=&v" dests, 64-bit vgpr-pair
// addresses + off, vmcnt(0) inside) -> compiler cannot interleave waits,
// true 18-deep MLP per wave.
// ---------------------------------------------------------------------------
__global__ __launch_bounds__(256, 2) void k_main(const ushort* __restrict__ xTb,
                                                 const float* __restrict__ om_pm,
                                                 const ushort* __restrict__ wB,
                                                 const float* __restrict__ bias,
                                                 float* __restrict__ out) {
    __shared__ __align__(16) char smem[NPIX * LDSROW];  // 18432 B
    __shared__ uint2 mw_lds[NPAIR];                     // 1152 B (f16x4)
    __shared__ ushort2 mo_lds[NPAIR];                   // 576 B  (off>>7)

    int tid = threadIdx.x;
    int lane = tid & 63;
    int wv = tid >> 6;
    int jb = blockIdx.x;
    int vb = (jb & 7) * 1024 + (jb >> 3);  // batch b -> XCD b
    int pb = vb * NPIX;
    int b = pb >> 14;
    int rem = pb & (HW - 1);
    int h = rem >> 7;
    int w0 = rem & (W - 1);

    // ---- Phase A0: per-(pixel,tap) slot metadata from pixel-major om ----
    if (tid < NPAIR) {
        int pix = tid / 9;
        int k = tid - pix * 9;
        const float* o0 = om_pm + ((size_t)b * HW + rem + pix) * 32;
        float offx = o0[k];
        float offy = o0[9 + k];
        float mlog = o0[18 + k];
        int dh = k / 3 - 1;
        int dw = k % 3 - 1;
        float mask = 1.0f / (1.0f + __expf(-mlog));
        float gx = (float)(w0 + pix + dw) + offx;
        float gy = (float)(h + dh) + offy;
        float x0f = floorf(gx), y0f = floorf(gy);
        int x0 = (int)x0f, y0 = (int)y0f;
        int x1 = x0 + 1, y1 = y0 + 1;
        float wx1 = gx - x0f, wy1 = gy - y0f;
        float wx0 = 1.0f - wx1, wy0 = 1.0f - wy1;
        float rw0 = ((unsigned)y0 < H) ? wy0 * mask : 0.0f;
        float rw1 = ((unsigned)y1 < H) ? wy1 * mask : 0.0f;
        int y0c = min(max(y0, 0), H - 1), y1c = min(max(y1, 0), H - 1);
        int colbase = min(max(x0, 0), W - 2);
        float cw0 = 0.0f, cw1 = 0.0f;
        if ((unsigned)x0 < W) { if (x0 == colbase) cw0 += wx0; else cw1 += wx0; }
        if ((unsigned)x1 < W) { if (x1 == colbase) cw0 += wx1; else cw1 += wx1; }
        mw_lds[tid] = make_uint2(pkhalf2(rw0 * cw0, rw0 * cw1),
                                 pkhalf2(rw1 * cw0, rw1 * cw1));
        mo_lds[tid] = make_ushort2((ushort)(((y0c * W + colbase) * (C * 2)) >> 7),
                                   (ushort)(((y1c * W + colbase) * (C * 2)) >> 7));
    }
    __syncthreads();

    // ---- Phase A1: single-asm 18-deep gather batch per pixel ----
    const char* xbase = (const char*)(xTb + (size_t)b * (HW * C));
    bool lo_half = lane < 32;
#pragma unroll 1
    for (int pp = 0; pp < 4; ++pp) {
        int p = wv * 4 + pp;
        uint2 mwv[KK];
        const char* a0p[KK];
        const char* a1p[KK];
#pragma unroll
        for (int k = 0; k < KK; ++k) {
            mwv[k] = mw_lds[p * 9 + k];
            ushort2 mo = mo_lds[p * 9 + k];
            a0p[k] = xbase + ((int)mo.x << 7) + lane * 4;
            a1p[k] = xbase + ((int)mo.y << 7) + lane * 4;
        }
        unsigned d0[KK], d1[KK];
        asm volatile(
            "global_load_dword %0, %18, off\n\t"
            "global_load_dword %1, %19, off\n\t"
            "global_load_dword %2, %20, off\n\t"
            "global_load_dword %3, %21, off\n\t"
            "global_load_dword %4, %22, off\n\t"
            "global_load_dword %5, %23, off\n\t"
            "global_load_dword %6, %24, off\n\t"
            "global_load_dword %7, %25, off\n\t"
            "global_load_dword %8, %26, off\n\t"
            "global_load_dword %9, %27, off\n\t"
            "global_load_dword %10, %28, off\n\t"
            "global_load_dword %11, %29, off\n\t"
            "global_load_dword %12, %30, off\n\t"
            "global_load_dword %13, %31, off\n\t"
            "global_load_dword %14, %32, off\n\t"
            "global_load_dword %15, %33, off\n\t"
            "global_load_dword %16, %34, off\n\t"
            "global_load_dword %17, %35, off\n\t"
            "s_waitcnt vmcnt(0)"
            : "=&v"(d0[0]), "=&v"(d0[1]), "=&v"(d0[2]), "=&v"(d0[3]),
              "=&v"(d0[4]), "=&v"(d0[5]), "=&v"(d0[6]), "=&v"(d0[7]),
              "=&v"(d0[8]),
              "=&v"(d1[0]), "=&v"(d1[1]), "=&v"(d1[2]), "=&v"(d1[3]),
              "=&v"(d1[4]), "=&v"(d1[5]), "=&v"(d1[6]), "=&v"(d1[7]),
              "=&v"(d1[8])
            : "v"(a0p[0]), "v"(a0p[1]), "v"(a0p[2]), "v"(a0p[3]),
              "v"(a0p[4]), "v"(a0p[5]), "v"(a0p[6]), "v"(a0p[7]),
              "v"(a0p[8]),
              "v"(a1p[0]), "v"(a1p[1]), "v"(a1p[2]), "v"(a1p[3]),
              "v"(a1p[4]), "v"(a1p[5]), "v"(a1p[6]), "v"(a1p[7]),
              "v"(a1p[8])
            : "memory");
        int vlds = p * LDSROW + (((lane & 31) * 4) ^ ((p & 7) << 4));
#pragma unroll
        for (int k = 0; k < KK; ++k) {
            __half2 h0 = *(__half2*)&mwv[k].x;
            __half2 h1 = *(__half2*)&mwv[k].y;
            float wa = lo_half ? __half2float(h0.x) : __half2float(h0.y);
            float wb_ = lo_half ? __half2float(h1.x) : __half2float(h1.y);
            float a0 = __uint_as_float(d0[k] << 16);
            float a1 = __uint_as_float(d0[k] & 0xFFFF0000u);
            float b0 = __uint_as_float(d1[k] << 16);
            float b1 = __uint_as_float(d1[k] & 0xFFFF0000u);
            float p0 = a0 * wa + b0 * wb_;
            float p1 = a1 * wa + b1 * wb_;
            float q0 = __shfl_xor(p0, 32, 64);
            float q1 = __shfl_xor(p1, 32, 64);
            float s0 = p0 + q0, s1 = p1 + q1;
            unsigned pk;
            asm("v_cvt_pk_bf16_f32 %0, %1, %2" : "=v"(pk) : "v"(s0), "v"(s1));
            if (lane < 32) *(unsigned*)(smem + vlds + k * 128) = pk;
        }
    }
    __syncthreads();

    // ---- Phase B: MFMA ----
    f32x4 acc;
#pragma unroll
    for (int j = 0; j < 4; ++j) acc[j] = bias[wv * 16 + (lane >> 4) * 4 + j];

    int pix = lane & 15;
    const ushort* wrow = wB + (size_t)(wv * 16 + pix) * KDIM + (lane >> 4) * 8;
#pragma unroll
    for (int s = 0; s < 18; ++s) {
        int kbyte = s * 64 + (lane >> 4) * 16;
        int byte = (pix * LDSROW + kbyte) ^ ((pix & 7) << 4);
        s16x8 bfrag = *(const s16x8*)(smem + byte);
        s16x8 afrag = *(const s16x8*)(wrow + s * 32);
        acc = __builtin_amdgcn_mfma_f32_16x16x32_bf16(afrag, bfrag, acc, 0, 0, 0);
    }

    float* obase = out + ((size_t)(b * COUT + wv * 16 + (lane >> 4) * 4) * HW) + h * W + w0;
#pragma unroll
    for (int j = 0; j < 4; ++j) obase[(size_t)j * HW + pix] = acc[j];
}

// ---------------------------------------------------------------------------
extern "C" void kernel_launch(void* const* d_in, const int* in_sizes, int n_in,
                              void* d_out, int out_size, void* d_ws, size_t ws_size,
                              hipStream_t stream) {
    const float* x = (const float*)d_in[0];
    const float* ow = (const float*)d_in[1];
    const float* ob = (const float*)d_in[2];
    const float* w = (const float*)d_in[3];
    const float* bias = (const float*)d_in[4];
    float* out = (float*)d_out;

    float* om_pm = (float*)d_ws;                          // B*HW*32 f = 16.8 MB
    ushort* xTb = (ushort*)(om_pm + (size_t)B * HW * 32); // B*HW*C ushort = 16.8 MB
    ushort* wB = xTb + (size_t)B * HW * C;                // 36864 ushort
    ushort* awB = wB + (size_t)COUT * KDIM;               // 18432 ushort
    // total ~33.7 MB

    hipLaunchKernelGGL(k_transpose_x, dim3(B * 256), dim3(256), 0, stream, x, xTb);
    hipLaunchKernelGGL(k_prep_w, dim3((COUT * KDIM + 255) / 256), dim3(256), 0,
                       stream, w, wB);
    hipLaunchKernelGGL(k_prep_aw, dim3((32 * KDIM + 255) / 256), dim3(256), 0,
                       stream, ow, awB);
    hipLaunchKernelGGL(k_om, dim3(B * H * 2), dim3(256), 0, stream, xTb, awB, ob, om_pm);
    hipLaunchKernelGGL(k_main, dim3(B * HW / NPIX), dim3(256), 0, stream,
                       xTb, om_pm, wB, bias, out);
}

// Round 22
// 156.273 us; speedup vs baseline: 1.0597x; 1.0597x over previous
//
#include <hip/hip_runtime.h>
#include <hip/hip_fp16.h>

#define B 8
#define C 64
#define H 128
#define W 128
#define HW (H * W)
#define OC 27
#define KK 9
#define COUT 64
#define KDIM 576           // 9*64
#define LDSROW 1152        // bytes per pixel row (576 * 2B)
#define NPIX 16            // pixels per k_main workgroup
#define NPAIR (NPIX * KK)  // 144

typedef __attribute__((ext_vector_type(8))) short s16x8;
typedef __attribute__((ext_vector_type(4))) float f32x4;

__device__ inline ushort f2bf(float f) {
    union { float f; unsigned u; } uv;
    uv.f = f;
    unsigned r = uv.u + 0x7FFF + ((uv.u >> 16) & 1);
    return (ushort)(r >> 16);
}
__device__ inline float bf2f(ushort u) {
    return __uint_as_float((unsigned)u << 16);
}
__device__ inline unsigned pkhalf2(float a, float b) {
    __half2 h = __floats2half2_rn(a, b);
    return *(unsigned*)&h;
}

// ---------------------------------------------------------------------------
// Kernel 1: transpose x (NCHW fp32) -> xTb (NHWC bf16). XCD-chunked swizzle.
// Stores vectorized: ushort2 per lane (2 channels), 2 hw-rows per wave-instr.
// ---------------------------------------------------------------------------
__global__ __launch_bounds__(256) void k_transpose_x(const float* __restrict__ x,
                                                     ushort* __restrict__ xTb) {
    __shared__ float lds[64][65];
    int j = blockIdx.x;
    int vb = (j & 7) * 256 + (j >> 3);
    int b = vb >> 8;
    int tile = vb & 255;
    int hw0 = tile * 64;
    int lane = threadIdx.x & 63;
    int cg = threadIdx.x >> 6;
#pragma unroll
    for (int r = 0; r < 16; ++r) {
        int c = cg * 16 + r;
        lds[c][lane] = x[(size_t)(b * C + c) * HW + hw0 + lane];
    }
    __syncthreads();
    int c2 = (lane & 31) * 2;
#pragma unroll
    for (int r = 0; r < 8; ++r) {
        int hwl = cg * 16 + r * 2 + (lane >> 5);
        ushort2 v;
        v.x = f2bf(lds[c2][hwl]);
        v.y = f2bf(lds[c2 + 1][hwl]);
        *(ushort2*)&xTb[(size_t)(b * HW + hw0 + hwl) * C + c2] = v;
    }
}

// ---------------------------------------------------------------------------
// Kernel 2: repack w -> wB[o][K] bf16, K = tap*64 + c.
// ---------------------------------------------------------------------------
__global__ __launch_bounds__(256) void k_prep_w(const float* __restrict__ w,
                                                ushort* __restrict__ wB) {
    int idx = blockIdx.x * 256 + threadIdx.x;
    if (idx >= COUT * KDIM) return;
    int o = idx / KDIM;
    int Kx = idx % KDIM;
    int k = Kx >> 6;
    int c = Kx & 63;
    wB[idx] = f2bf(w[(size_t)(o * C + c) * KK + k]);
}

// ---------------------------------------------------------------------------
// Kernel 2b: repack ow -> awB[32][576] bf16 (rows 27..31 = 0).
// ---------------------------------------------------------------------------
__global__ __launch_bounds__(256) void k_prep_aw(const float* __restrict__ ow,
                                                 ushort* __restrict__ awB) {
    int idx = blockIdx.x * 256 + threadIdx.x;
    if (idx >= 32 * KDIM) return;
    int o = idx / KDIM;
    int Kx = idx % KDIM;
    int tap = Kx >> 6;
    int c = Kx & 63;
    float v = (o < OC) ? ow[((size_t)o * C + c) * KK + tap] : 0.0f;
    awB[idx] = f2bf(v);
}

// ---------------------------------------------------------------------------
// Kernel 3: offset/mask conv (im2col MFMA GEMM); uint4 staging; om written
// pixel-major [b][hw][32].
// ---------------------------------------------------------------------------
__global__ __launch_bounds__(256) void k_om(const ushort* __restrict__ xTb,
                                            const ushort* __restrict__ awB,
                                            const float* __restrict__ ob,
                                            float* __restrict__ om_pm) {
    __shared__ __align__(16) char xwin[3 * 66 * 128];  // 25344 B
    int tid = threadIdx.x;
    int lane = tid & 63;
    int wv = tid >> 6;
    int j = blockIdx.x;
    int vb = (j & 7) * 256 + (j >> 3);
    int b = vb >> 8;
    int h = (vb >> 1) & 127;
    int w0 = (vb & 1) * 64;

    const char* xb = (const char*)(xTb + (size_t)b * (HW * C));
#pragma unroll
    for (int i = 0; i < 7; ++i) {
        int idx = i * 256 + tid;
        if (idx < 198 * 8) {
            int pi = idx >> 3;
            int ch16 = idx & 7;
            int row = pi / 66;
            int col = pi - row * 66;
            int y = h - 1 + row;
            int xc = w0 - 1 + col;
            uint4 v = make_uint4(0, 0, 0, 0);
            if ((unsigned)y < H && (unsigned)xc < W)
                v = *(const uint4*)(xb + ((size_t)((y << 7) + xc) << 7) + ch16 * 16);
            int byte = (pi * 128 + ch16 * 16) ^ ((col & 7) << 4);
            *(uint4*)(xwin + byte) = v;
        }
    }
    __syncthreads();

    f32x4 acc0 = {0.f, 0.f, 0.f, 0.f};
    f32x4 acc1 = {0.f, 0.f, 0.f, 0.f};
    int pixl = lane & 15;
    int q = lane >> 4;
    int base_col = wv * 16 + pixl;
    const ushort* a0 = awB + (size_t)pixl * KDIM + q * 8;
    const ushort* a1 = awB + (size_t)(16 + pixl) * KDIM + q * 8;
#pragma unroll
    for (int s = 0; s < 18; ++s) {
        int tap = s >> 1;
        int row = tap / 3;
        int cs = tap - row * 3;
        int col = base_col + cs;
        int c0b = ((s & 1) * 32 + q * 8) * 2;
        int byte = (((row * 66 + col) << 7) + c0b) ^ ((col & 7) << 4);
        s16x8 bfrag = *(const s16x8*)(xwin + byte);
        s16x8 af0 = *(const s16x8*)(a0 + s * 32);
        s16x8 af1 = *(const s16x8*)(a1 + s * 32);
        acc0 = __builtin_amdgcn_mfma_f32_16x16x32_bf16(af0, bfrag, acc0, 0, 0, 0);
        acc1 = __builtin_amdgcn_mfma_f32_16x16x32_bf16(af1, bfrag, acc1, 0, 0, 0);
    }

    __syncthreads();
    float* omt = (float*)xwin;  // [64 pix][29]
    {
        int pix = wv * 16 + pixl;
#pragma unroll
        for (int jj = 0; jj < 4; ++jj) {
            int oc = q * 4 + jj;
            omt[pix * 29 + oc] = acc0[jj] + ob[oc];
        }
#pragma unroll
        for (int jj = 0; jj < 4; ++jj) {
            int oc1 = 16 + q * 4 + jj;
            if (oc1 < OC) omt[pix * 29 + oc1] = acc1[jj] + ob[oc1];
        }
    }
    __syncthreads();

    float* dst = om_pm + ((size_t)b * HW + h * W + w0) * 32;
#pragma unroll
    for (int t = tid; t < 64 * 32; t += 256) {
        int pix = t >> 5;
        int oc = t & 31;
        float v = (oc < OC) ? omt[pix * 29 + oc] : 0.0f;
        dst[(size_t)pix * 32 + oc] = v;
    }
}

// ---------------------------------------------------------------------------
// Kernel 4: fused deformable sampling + MFMA einsum (best-known: R14/R17
// configuration, 112 µs). 20480 B LDS; f16-packed meta; batched row gathers.
// ---------------------------------------------------------------------------
__global__ __launch_bounds__(256) void k_main(const ushort* __restrict__ xTb,
                                              const float* __restrict__ om_pm,
                                              const ushort* __restrict__ wB,
                                              const float* __restrict__ bias,
                                              float* __restrict__ out) {
    __shared__ __align__(16) char smem[NPIX * LDSROW];  // 18432 B
    __shared__ uint2 mw_lds[NPAIR];                     // 1152 B (f16x4)
    __shared__ ushort2 mo_lds[NPAIR];                   // 576 B  (off>>7)

    int tid = threadIdx.x;
    int lane = tid & 63;
    int wv = tid >> 6;
    int jb = blockIdx.x;
    int vb = (jb & 7) * 1024 + (jb >> 3);  // batch b -> XCD b
    int pb = vb * NPIX;
    int b = pb >> 14;
    int rem = pb & (HW - 1);
    int h = rem >> 7;
    int w0 = rem & (W - 1);

    // ---- Phase A0: per-(pixel,tap) slot metadata from pixel-major om ----
    if (tid < NPAIR) {
        int pix = tid / 9;
        int k = tid - pix * 9;
        const float* o0 = om_pm + ((size_t)b * HW + rem + pix) * 32;
        float offx = o0[k];
        float offy = o0[9 + k];
        float mlog = o0[18 + k];
        int dh = k / 3 - 1;
        int dw = k % 3 - 1;
        float mask = 1.0f / (1.0f + __expf(-mlog));
        float gx = (float)(w0 + pix + dw) + offx;
        float gy = (float)(h + dh) + offy;
        float x0f = floorf(gx), y0f = floorf(gy);
        int x0 = (int)x0f, y0 = (int)y0f;
        int x1 = x0 + 1, y1 = y0 + 1;
        float wx1 = gx - x0f, wy1 = gy - y0f;
        float wx0 = 1.0f - wx1, wy0 = 1.0f - wy1;
        float rw0 = ((unsigned)y0 < H) ? wy0 * mask : 0.0f;
        float rw1 = ((unsigned)y1 < H) ? wy1 * mask : 0.0f;
        int y0c = min(max(y0, 0), H - 1), y1c = min(max(y1, 0), H - 1);
        int colbase = min(max(x0, 0), W - 2);
        float cw0 = 0.0f, cw1 = 0.0f;
        if ((unsigned)x0 < W) { if (x0 == colbase) cw0 += wx0; else cw1 += wx0; }
        if ((unsigned)x1 < W) { if (x1 == colbase) cw0 += wx1; else cw1 += wx1; }
        mw_lds[tid] = make_uint2(pkhalf2(rw0 * cw0, rw0 * cw1),
                                 pkhalf2(rw1 * cw0, rw1 * cw1));
        mo_lds[tid] = make_ushort2((ushort)(((y0c * W + colbase) * (C * 2)) >> 7),
                                   (ushort)(((y1c * W + colbase) * (C * 2)) >> 7));
    }
    __syncthreads();

    // ---- Phase A1: batched full-wave row gathers ----
    const char* xbase = (const char*)(xTb + (size_t)b * (HW * C));
    bool lo_half = lane < 32;
#pragma unroll 1
    for (int pp = 0; pp < 4; ++pp) {
        int p = wv * 4 + pp;
        uint2 mwv[KK];
        int mo0[KK], mo1[KK];
#pragma unroll
        for (int k = 0; k < KK; ++k) {
            mwv[k] = mw_lds[p * 9 + k];
            ushort2 mo = mo_lds[p * 9 + k];
            mo0[k] = (int)mo.x << 7;
            mo1[k] = (int)mo.y << 7;
        }
        unsigned d0[KK], d1[KK];
#pragma unroll
        for (int k = 0; k < KK; ++k) {
            d0[k] = *(const unsigned*)(xbase + mo0[k] + lane * 4);
            d1[k] = *(const unsigned*)(xbase + mo1[k] + lane * 4);
        }
        __builtin_amdgcn_sched_barrier(0);
        int vlds = p * LDSROW + (((lane & 31) * 4) ^ ((p & 7) << 4));
#pragma unroll
        for (int k = 0; k < KK; ++k) {
            __half2 h0 = *(__half2*)&mwv[k].x;
            __half2 h1 = *(__half2*)&mwv[k].y;
            float wa = lo_half ? __half2float(h0.x) : __half2float(h0.y);
            float wb_ = lo_half ? __half2float(h1.x) : __half2float(h1.y);
            float a0 = __uint_as_float(d0[k] << 16);
            float a1 = __uint_as_float(d0[k] & 0xFFFF0000u);
            float b0 = __uint_as_float(d1[k] << 16);
            float b1 = __uint_as_float(d1[k] & 0xFFFF0000u);
            float p0 = a0 * wa + b0 * wb_;
            float p1 = a1 * wa + b1 * wb_;
            float q0 = __shfl_xor(p0, 32, 64);
            float q1 = __shfl_xor(p1, 32, 64);
            float s0 = p0 + q0, s1 = p1 + q1;
            unsigned pk;
            asm("v_cvt_pk_bf16_f32 %0, %1, %2" : "=v"(pk) : "v"(s0), "v"(s1));
            if (lane < 32) *(unsigned*)(smem + vlds + k * 128) = pk;
        }
    }
    __syncthreads();

    // ---- Phase B: MFMA ----
    f32x4 acc;
#pragma unroll
    for (int j = 0; j < 4; ++j) acc[j] = bias[wv * 16 + (lane >> 4) * 4 + j];

    int pix = lane & 15;
    const ushort* wrow = wB + (size_t)(wv * 16 + pix) * KDIM + (lane >> 4) * 8;
#pragma unroll
    for (int s = 0; s < 18; ++s) {
        int kbyte = s * 64 + (lane >> 4) * 16;
        int byte = (pix * LDSROW + kbyte) ^ ((pix & 7) << 4);
        s16x8 bfrag = *(const s16x8*)(smem + byte);
        s16x8 afrag = *(const s16x8*)(wrow + s * 32);
        acc = __builtin_amdgcn_mfma_f32_16x16x32_bf16(afrag, bfrag, acc, 0, 0, 0);
    }

    float* obase = out + ((size_t)(b * COUT + wv * 16 + (lane >> 4) * 4) * HW) + h * W + w0;
#pragma unroll
    for (int j = 0; j < 4; ++j) obase[(size_t)j * HW + pix] = acc[j];
}

// ---------------------------------------------------------------------------
extern "C" void kernel_launch(void* const* d_in, const int* in_sizes, int n_in,
                              void* d_out, int out_size, void* d_ws, size_t ws_size,
                              hipStream_t stream) {
    const float* x = (const float*)d_in[0];
    const float* ow = (const float*)d_in[1];
    const float* ob = (const float*)d_in[2];
    const float* w = (const float*)d_in[3];
    const float* bias = (const float*)d_in[4];
    float* out = (float*)d_out;

    float* om_pm = (float*)d_ws;                          // B*HW*32 f = 16.8 MB
    ushort* xTb = (ushort*)(om_pm + (size_t)B * HW * 32); // B*HW*C ushort = 16.8 MB
    ushort* wB = xTb + (size_t)B * HW * C;                // 36864 ushort
    ushort* awB = wB + (size_t)COUT * KDIM;               // 18432 ushort
    // total ~33.7 MB

    hipLaunchKernelGGL(k_transpose_x, dim3(B * 256), dim3(256), 0, stream, x, xTb);
    hipLaunchKernelGGL(k_prep_w, dim3((COUT * KDIM + 255) / 256), dim3(256), 0,
                       stream, w, wB);
    hipLaunchKernelGGL(k_prep_aw, dim3((32 * KDIM + 255) / 256), dim3(256), 0,
                       stream, ow, awB);
    hipLaunchKernelGGL(k_om, dim3(B * H * 2), dim3(256), 0, stream, xTb, awB, ob, om_pm);
    hipLaunchKernelGGL(k_main, dim3(B * HW / NPIX), dim3(256), 0, stream,
                       xTb, om_pm, wB, bias, out);
}